// Round 6
// baseline (7240.896 us; speedup 1.0000x reference)
//
#include <hip/hip_runtime.h>

// ---------------------------------------------------------------------------
// RNN_Layer: x[B,T,C] fp32 -> conv1x1(w_in) -> dense(kernel) -> LSTM(rec)
//            -> dense(w_out).  B=32 T=1024 C=512 D=256 U=256 O=256.
// R12: PERSISTENT CROSS-CU LSTM.  All within-CU structures (R6-R11) floor at
// >=4100 cyc/step: batch-per-CU forces MFMA M=1 (26 MAC/cyc/SIMD) and W
// residency vs the 256-arch-VGPR cap (R10/R11: pinned arrays -> AGPR/scratch).
// New partition: 32 WGs x 256 thr, WG g owns UNITS 8g..8g+7 (32 gate-cols)
// for ALL 32 batches.  W slice = 16 KB -> B-frags in 32 VGPRs/wave (fully
// resident, trivially).  MFMA M=16 batches (full rows): 8 mfma/wave/step.
// Cross-WG h exchange per step through MALL:
//   h ping-pong buffers by parity; relaxed AGENT-scope atomic u64 loads /
//   u32 stores (sc1, always coherent, compiler-tracked); per-WG tag word,
//   release-stored after a release-fence + __syncthreads drain; consumers
//   poll all 32 tags with one 64-lane sc1 load + __all.
//   Seeing tags>=t  =>  every WG finished step t-1 (reads of h_{t-1} done)
//   =>  overwriting hbuf[(t+1)&1] is race-free.  Bounded spin (2^20) turns a
//   placement pathology into a visible wrong-answer, not a hang.
// Step model: poll RT ~0.25-0.5us + A loads ~0.2 + mfma/gates ~0.15 +
// publish ~0.1  =>  ~0.7-1.2us/step vs R7's 1.73.
// ---------------------------------------------------------------------------

#define DEV static __device__ __forceinline__

typedef __attribute__((ext_vector_type(8))) short short8;
typedef __attribute__((ext_vector_type(4))) float floatx4;
typedef _Float16 half8 __attribute__((ext_vector_type(8)));

static constexpr int Bsz = 32, T = 1024, C = 512, D = 256, U = 256, FU = 1024;
static constexpr int M = Bsz * T;   // 32768 rows for all GEMMs

DEV float bfu2f(unsigned int u) { union { unsigned int i; float f; } v; v.i = u; return v.f; }
DEV float bf2f(unsigned short u) { return bfu2f(((unsigned int)u) << 16); }
DEV unsigned short f2bf(float f) {
    union { float f; unsigned int i; } v; v.f = f;
    return (unsigned short)((v.i + 0x7fffu + ((v.i >> 16) & 1u)) >> 16);
}
DEV float sigmf(float x) { return 1.0f / (1.0f + __expf(-x)); }
DEV float tanhfast(float x) {
    const float a = __expf(-2.0f * fabsf(x));
    const float t = (1.0f - a) / (1.0f + a);
    return copysignf(t, x);
}
DEV half8 h8c(uint4 v) { return __builtin_bit_cast(half8, v); }

// fp32-or-bf16 element -> bf16 bit pattern (GEMM operand loads)
DEV short ld_bf(const float* p) { return (short)f2bf(*p); }
DEV short ld_bf(const unsigned short* p) { return (short)*p; }
DEV short8 ld_frag(const unsigned short* p) { return *(const short8*)p; }
DEV short8 ld_frag(const float* p) {
    short8 v;
#pragma unroll
    for (int j = 0; j < 8; j++) v[j] = (short)f2bf(p[j]);
    return v;
}
DEV float ldxz1(const float* p) { return *p; }
DEV float ldxz1(const unsigned short* p) { return bf2f(*p); }

// lgkm-only barrier (intra-WG LDS visibility without draining vmem)
#define BAR() asm volatile("s_waitcnt lgkmcnt(0)\n\ts_barrier" ::: "memory")

// ---------------------------------------------------------------------------
// Fragment-direct MFMA GEMM:  C[M,N] = A[M,K] @ B[K,N] + bias[N]
// Layouts (m89/m120-verified): A[m=lane&15][k=quad*8+j];
//   B[k=quad*8+j][n=lane&15]; D[m=quad*4+r][n=lane&15]
// ---------------------------------------------------------------------------
template <int K, int N, int MT, int NS, bool OUTF32, typename AT, typename BT>
__global__ __launch_bounds__(64) void gemm_mfma(
    const AT* __restrict__ A,
    const BT* __restrict__ Bm,
    const float* __restrict__ bias,
    void* __restrict__ Cv)
{
    constexpr int KC = K / 32;
    const int lane = threadIdx.x;
    const int quad = lane >> 4, lr = lane & 15;
    constexpr int NSG = N / (16 * NS);
    const int sg = blockIdx.x % NSG;
    const int mb = blockIdx.x / NSG;
    const int n0 = sg * 16 * NS;

    short8 bf[NS][KC];
    float biasv[NS];
#pragma unroll
    for (int s = 0; s < NS; s++) {
        const int n = n0 + s * 16 + lr;
        biasv[s] = bias[n];
#pragma unroll
        for (int kc = 0; kc < KC; kc++) {
            short8 v;
#pragma unroll
            for (int j = 0; j < 8; j++) {
                const int k = kc * 32 + quad * 8 + j;
                v[j] = ld_bf(&Bm[(size_t)k * N + n]);
            }
            bf[s][kc] = v;
        }
    }

    for (int mt = 0; mt < MT; mt++) {
        const int m0 = (mb * MT + mt) * 16;
        const AT* Ap = A + (size_t)(m0 + lr) * K + quad * 8;
        floatx4 acc[NS];
#pragma unroll
        for (int s = 0; s < NS; s++) acc[s] = (floatx4){0.f, 0.f, 0.f, 0.f};
#pragma unroll
        for (int kc = 0; kc < KC; kc++) {
            short8 af = ld_frag(Ap + kc * 32);
#pragma unroll
            for (int s = 0; s < NS; s++)
                acc[s] = __builtin_amdgcn_mfma_f32_16x16x32_bf16(af, bf[s][kc], acc[s], 0, 0, 0);
        }
#pragma unroll
        for (int s = 0; s < NS; s++) {
            const int n = n0 + s * 16 + lr;
#pragma unroll
            for (int r = 0; r < 4; r++) {
                const int m = m0 + quad * 4 + r;
                const float val = acc[s][r] + biasv[s];
                if (OUTF32)
                    ((float*)Cv)[(size_t)m * N + n] = val;
                else
                    ((unsigned short*)Cv)[(size_t)m * N + n] = f2bf(val);
            }
        }
    }
}

// ---------------------------------------------------------------------------
// Pack rec_kernel fp32 [256][1024] -> per-(WG,nt) f16 MFMA B-fragments.
// Pp[((g*2+nt)*8+kc)*64+lane].j = f16( rec[kc*32+(lane>>4)*8+j][gcol] )
// where c=nt*16+(lane&15), gcol = 256*(c>>3) + 8*g + (c&7)
// (col-local c: 0-7=i,8-15=f,16-23=g,24-31=o for units 8g..8g+7).
// ---------------------------------------------------------------------------
__global__ __launch_bounds__(256) void pack_rec_pp(const float* __restrict__ rec,
                                                   uint4* __restrict__ Pp)
{
    const int idx = blockIdx.x * 256 + threadIdx.x;   // 0..32767
    const int lane = idx & 63;
    const int kc = (idx >> 6) & 7;
    const int gnt = idx >> 9;                         // g*2+nt
    const int g = gnt >> 1, nt = gnt & 1;
    const int q = lane >> 4, lr = lane & 15;
    const int c = nt * 16 + lr;
    const int gcol = 256 * (c >> 3) + 8 * g + (c & 7);
    const int k0 = kc * 32 + q * 8;
    union { unsigned short u[8]; uint4 v; } out;
#pragma unroll
    for (int j = 0; j < 8; j++) {
        const _Float16 h = (_Float16)rec[(size_t)(k0 + j) * FU + gcol];
        out.u[j] = __builtin_bit_cast(unsigned short, h);
    }
    Pp[idx] = out.v;
}

// zero h ping-pong parity 0 (h_0 = 0) and the 32 tag words (every launch:
// ws is re-poisoned, and graph replays must re-arm the sync state).
__global__ __launch_bounds__(256) void init_sync(unsigned long long* __restrict__ hbuf,
                                                 unsigned int* __restrict__ tags)
{
    const int i = blockIdx.x * 256 + threadIdx.x;
    if (i < 2048) hbuf[i] = 0ULL;        // 16 KiB parity-0 h
    if (i < 32) tags[i] = 0u;
}

// ---------------------------------------------------------------------------
// Persistent cross-CU LSTM.  32 WGs x 256 thr (4 waves).  Wave w=(mt,nt):
// mt = batch-tile (16 batches), nt = col-tile (16 of this WG's 32 cols).
// Per step per wave: 8 coherent u64-pair A loads + 8 mfma 16x16x32 f16.
// Gate phase: thread = (batch gb, unit gu) via zsh LDS (pad 33 = no conflicts).
// c-state lives in a register for all 1024 steps.
// ---------------------------------------------------------------------------
template <typename XZT>
__global__ __launch_bounds__(256, 1)
void lstm_persist(
    const XZT* __restrict__ xz,              // [B, T, 4U]
    const uint4* __restrict__ Pp,            // packed B-frags
    unsigned long long* __restrict__ hbuf,   // [2][B*U] f16 (u64 view)
    unsigned int* __restrict__ tags,         // [32]
    unsigned short* __restrict__ hs)         // [B, T, U] bf16 out
{
    const int g = blockIdx.x;
    const int tid = threadIdx.x;
    const int w = tid >> 6, lane = tid & 63;
    const int q = lane >> 4, lr = lane & 15;
    const int mt = w >> 1, nt = w & 1;
    const int gb = tid >> 3, gu = tid & 7;   // gate phase: batch, local unit
    const int ucol = 8 * g + gu;             // global unit index

    __shared__ float zsh[32 * 33];           // z[batch][col-local], padded

    // resident B-frags for this wave's 16 columns: 32 VGPRs
    uint4 Wn[8];
#pragma unroll
    for (int kc = 0; kc < 8; kc++)
        Wn[kc] = Pp[(size_t)((g * 2 + nt) * 8 + kc) * 64 + lane];
#pragma unroll
    for (int kc = 0; kc < 8; kc++)
        asm volatile("" : "+v"(Wn[kc].x), "+v"(Wn[kc].y), "+v"(Wn[kc].z), "+v"(Wn[kc].w));

    float cst = 0.f;
    int alive = 1;
    const size_t xzbase = (size_t)gb * T * FU + ucol;

    for (int t = 0; t < T; t++) {
        // xz[t] for this thread's gates: plain cached loads, no h dependency;
        // issued before the poll so their latency hides under it.
        const XZT* xt = xz + xzbase + (size_t)t * FU;
        const float xzi = ldxz1(xt);
        const float xzf = ldxz1(xt + 256);
        const float xzg = ldxz1(xt + 512);
        const float xzo = ldxz1(xt + 768);

        // wait until every WG has published h_t (tags >= t)
        if (t > 0 && alive) {
            int ok = 0;
            for (int spin = 0; spin < (1 << 20); ++spin) {
                const unsigned int tg = __hip_atomic_load(
                    &tags[lane & 31], __ATOMIC_RELAXED, __HIP_MEMORY_SCOPE_AGENT);
                if (__all((int)(tg >= (unsigned int)t))) { ok = 1; break; }
            }
            alive = ok;   // bounded: pathological placement -> visible fail, not hang
            __builtin_amdgcn_fence(__ATOMIC_ACQUIRE, "agent");
        }

        // A-frags: h_t[batch mt*16+lr][kc*32+q*8 .. +7] as coherent u64 pairs
        const unsigned long long* hb =
            hbuf + (size_t)(t & 1) * 2048 + (size_t)(mt * 16 + lr) * 64;
        uint4 A[8];
#pragma unroll
        for (int kc = 0; kc < 8; kc++) {
            const unsigned long long lo = __hip_atomic_load(
                hb + kc * 8 + q * 2,     __ATOMIC_RELAXED, __HIP_MEMORY_SCOPE_AGENT);
            const unsigned long long hi = __hip_atomic_load(
                hb + kc * 8 + q * 2 + 1, __ATOMIC_RELAXED, __HIP_MEMORY_SCOPE_AGENT);
            A[kc].x = (unsigned int)lo; A[kc].y = (unsigned int)(lo >> 32);
            A[kc].z = (unsigned int)hi; A[kc].w = (unsigned int)(hi >> 32);
        }

        floatx4 acc = {0.f, 0.f, 0.f, 0.f};
#pragma unroll
        for (int kc = 0; kc < 8; kc++)
            acc = __builtin_amdgcn_mfma_f32_16x16x32_f16(h8c(A[kc]), h8c(Wn[kc]), acc, 0, 0, 0);

        // publish z-tile to LDS: D[m=q*4+r][n=lr]
#pragma unroll
        for (int r = 0; r < 4; r++)
            zsh[(mt * 16 + q * 4 + r) * 33 + nt * 16 + lr] = acc[r];
        BAR();

        // gates (Keras i,f,g,o) for (batch gb, unit ucol)
        const float zi = zsh[gb * 33 + gu]      + xzi;
        const float zf = zsh[gb * 33 + 8 + gu]  + xzf;
        const float zg = zsh[gb * 33 + 16 + gu] + xzg;
        const float zo = zsh[gb * 33 + 24 + gu] + xzo;
        const float iv = sigmf(zi), fv = sigmf(zf);
        const float gv = tanhfast(zg), ov = sigmf(zo);
        cst = fv * cst + iv * gv;
        const float hv = ov * tanhfast(cst);

        hs[(size_t)gb * T * U + (size_t)t * U + ucol] = f2bf(hv);

        // h_{t+1} -> hbuf[(t+1)&1]: pair up f16 via shfl, u32 agent stores
        const unsigned int hbits =
            (unsigned int)__builtin_bit_cast(unsigned short, (_Float16)hv);
        const unsigned int nbits = __shfl_down(hbits, 1);
        if ((gu & 1) == 0) {
            unsigned int* dst = (unsigned int*)hbuf
                + (size_t)((t + 1) & 1) * 4096 + (size_t)gb * 128 + (ucol >> 1);
            __hip_atomic_store(dst, hbits | (nbits << 16),
                               __ATOMIC_RELAXED, __HIP_MEMORY_SCOPE_AGENT);
        }
        // all threads drain their h stores, then one tag release-store
        __builtin_amdgcn_fence(__ATOMIC_RELEASE, "agent");
        __syncthreads();
        if (tid == 0)
            __hip_atomic_store(&tags[g], (unsigned int)(t + 1),
                               __ATOMIC_RELEASE, __HIP_MEMORY_SCOPE_AGENT);
    }
}

// ---------------------------------------------------------------------------
extern "C" void kernel_launch(void* const* d_in, const int* in_sizes, int n_in,
                              void* d_out, int out_size, void* d_ws, size_t ws_size,
                              hipStream_t stream)
{
    const float* x    = (const float*)d_in[0];
    const float* w_in = (const float*)d_in[1];
    const float* b_in = (const float*)d_in[2];
    const float* kern = (const float*)d_in[3];
    const float* rec  = (const float*)d_in[4];
    const float* bias = (const float*)d_in[5];
    const float* wout = (const float*)d_in[6];
    const float* bout = (const float*)d_in[7];

    char* ws = (char*)d_ws;
    const size_t pp_bytes  = (size_t)32768 * 16;      // 512 KiB packed B-frags
    const size_t hb_bytes  = (size_t)32 * 1024;       // 32 KiB h ping-pong
    const size_t tg_bytes  = (size_t)4096;            // tags (+pad)
    const size_t rec_bytes = pp_bytes + hb_bytes + tg_bytes;
    const size_t xin_bytes = (size_t)M * D * 2;       // 16 MiB
    const size_t hs_bytes  = (size_t)M * U * 2;       // 16 MiB
    const size_t xz32_bytes = (size_t)M * FU * 4;     // 128 MiB
    const size_t base = rec_bytes + xin_bytes + hs_bytes;

    uint4* Pp = (uint4*)ws;
    unsigned long long* hbuf = (unsigned long long*)(ws + pp_bytes);
    unsigned int* tags = (unsigned int*)(ws + pp_bytes + hb_bytes);
    unsigned short* xin_bf = (unsigned short*)(ws + rec_bytes);
    unsigned short* hs_bf  = (unsigned short*)(ws + rec_bytes + xin_bytes);
    char* xz_raw = ws + base;

    const bool use_f32 = ws_size >= base + xz32_bytes;

    // pack rec_kernel + arm the sync state (every launch; ws re-poisoned)
    pack_rec_pp<<<128, 256, 0, stream>>>(rec, Pp);
    init_sync<<<8, 256, 0, stream>>>(hbuf, tags);

    // GEMM1: xin = bf16(x @ w_in + b_in)   [M,512]x[512,256]
    gemm_mfma<512, 256, 16, 2, false><<<(256 / 32) * (M / 256), 64, 0, stream>>>(
        x, w_in, b_in, (void*)xin_bf);

    if (use_f32) {
        float* xzp = (float*)xz_raw;
        // GEMM2: xz = fp32(xin @ kernel + bias)  [M,256]x[256,1024]
        gemm_mfma<256, 1024, 16, 2, true><<<(1024 / 32) * (M / 256), 64, 0, stream>>>(
            xin_bf, kern, bias, (void*)xzp);
        lstm_persist<float><<<32, 256, 0, stream>>>(xzp, Pp, hbuf, tags, hs_bf);
    } else {
        unsigned short* xzp = (unsigned short*)xz_raw;
        gemm_mfma<256, 1024, 16, 2, false><<<(1024 / 32) * (M / 256), 64, 0, stream>>>(
            xin_bf, kern, bias, (void*)xzp);
        lstm_persist<unsigned short><<<32, 256, 0, stream>>>(xzp, Pp, hbuf, tags, hs_bf);
    }

    // GEMM3: out = fp32(hs @ w_out + b_out)  [M,256]x[256,256]
    gemm_mfma<256, 256, 16, 2, true><<<(256 / 32) * (M / 256), 64, 0, stream>>>(
        hs_bf, wout, bout, d_out);
}

// Round 7
// 1881.319 us; speedup vs baseline: 3.8488x; 3.8488x over previous
//
#include <hip/hip_runtime.h>

// ---------------------------------------------------------------------------
// RNN_Layer: x[B,T,C] fp32 -> conv1x1(w_in) -> dense(kernel) -> LSTM(rec)
//            -> dense(w_out).  B=32 T=1024 C=512 D=256 U=256 O=256.
// R13: refined single-pipe MFMA LSTM (R7 structure + 4 measured fixes).
// R12 post-mortem: cross-CU h-exchange = ~6.7us/step (FETCH 330MB) -> dead;
// within-CU MFMA floor = 128 mfma/SIMD/step x 19.4cyc = 2480cyc = 1.03us.
// R7 ran 1.73us/step; the gap was (a) divergent lr==0 A-loads, (b) "+v"
// pinning 192 W regs into a 128-arch-VGPR budget (per-step shuffle/spill),
// (c) 2x full-drain __syncthreads, (d) 16-lane gate tail.
// Fixes here:
//   a) broadcast-A (R10-verified): all lanes read the same h-frag per kc ->
//      all 16 A rows = h -> every D row = z; 8 uniform ds_reads/step/wave.
//   b) wave w owns strips {2w,2w+1, 16+2w,17+2w, 32+2w,33+2w} resident with
//      4 strips pinned "+a" (128 AGPR, MFMA reads B from AGPR natively) +
//      2 strips "+v" (64 arch); o-strips {48+2w,49+2w} streamed from LDS.
//      Total 252 <= 256 unified regs/wave at 2 waves/SIMD.
//   c) h double-buffered by parity -> ONE lgkm-only barrier per step.
//   d) strip pairing (i,i,f,f,g,g,o,o) -> lane (q<2,lr) holds all 4 gate
//      z's of unit 32w+16q+lr in acc[*][0] -> 32 lanes/wave gate phase,
//      no z LDS roundtrip.
// ---------------------------------------------------------------------------

#define DEV static __device__ __forceinline__

typedef __attribute__((ext_vector_type(8))) short short8;
typedef __attribute__((ext_vector_type(4))) float floatx4;
typedef _Float16 half8 __attribute__((ext_vector_type(8)));

static constexpr int Bsz = 32, T = 1024, C = 512, D = 256, U = 256, FU = 1024;
static constexpr int M = Bsz * T;   // 32768 rows for all GEMMs

DEV float bfu2f(unsigned int u) { union { unsigned int i; float f; } v; v.i = u; return v.f; }
DEV float bf2f(unsigned short u) { return bfu2f(((unsigned int)u) << 16); }
DEV unsigned short f2bf(float f) {
    union { float f; unsigned int i; } v; v.f = f;
    return (unsigned short)((v.i + 0x7fffu + ((v.i >> 16) & 1u)) >> 16);
}
DEV float sigmf(float x) { return 1.0f / (1.0f + __expf(-x)); }
DEV float tanhfast(float x) {
    const float a = __expf(-2.0f * fabsf(x));
    const float t = (1.0f - a) / (1.0f + a);
    return copysignf(t, x);
}
DEV half8 h8c(uint4 v) { return __builtin_bit_cast(half8, v); }

// fp32-or-bf16 element -> bf16 bit pattern (GEMM operand loads)
DEV short ld_bf(const float* p) { return (short)f2bf(*p); }
DEV short ld_bf(const unsigned short* p) { return (short)*p; }
DEV short8 ld_frag(const unsigned short* p) { return *(const short8*)p; }
DEV short8 ld_frag(const float* p) {
    short8 v;
#pragma unroll
    for (int j = 0; j < 8; j++) v[j] = (short)f2bf(p[j]);
    return v;
}
DEV float ldxz1(const float* p) { return *p; }
DEV float ldxz1(const unsigned short* p) { return bf2f(*p); }

// lgkm-only barrier: cross-thread data is LDS-only; don't drain vmcnt
// (xz prefetch loads / hs stores stay in flight across steps).
#define BAR() asm volatile("s_waitcnt lgkmcnt(0)\n\ts_barrier" ::: "memory")

// ---------------------------------------------------------------------------
// Fragment-direct MFMA GEMM:  C[M,N] = A[M,K] @ B[K,N] + bias[N]
// Layouts (m89/m120-verified): A[m=lane&15][k=quad*8+j];
//   B[k=quad*8+j][n=lane&15]; D[m=quad*4+r][n=lane&15]
// ---------------------------------------------------------------------------
template <int K, int N, int MT, int NS, bool OUTF32, typename AT, typename BT>
__global__ __launch_bounds__(64) void gemm_mfma(
    const AT* __restrict__ A,
    const BT* __restrict__ Bm,
    const float* __restrict__ bias,
    void* __restrict__ Cv)
{
    constexpr int KC = K / 32;
    const int lane = threadIdx.x;
    const int quad = lane >> 4, lr = lane & 15;
    constexpr int NSG = N / (16 * NS);
    const int sg = blockIdx.x % NSG;
    const int mb = blockIdx.x / NSG;
    const int n0 = sg * 16 * NS;

    short8 bf[NS][KC];
    float biasv[NS];
#pragma unroll
    for (int s = 0; s < NS; s++) {
        const int n = n0 + s * 16 + lr;
        biasv[s] = bias[n];
#pragma unroll
        for (int kc = 0; kc < KC; kc++) {
            short8 v;
#pragma unroll
            for (int j = 0; j < 8; j++) {
                const int k = kc * 32 + quad * 8 + j;
                v[j] = ld_bf(&Bm[(size_t)k * N + n]);
            }
            bf[s][kc] = v;
        }
    }

    for (int mt = 0; mt < MT; mt++) {
        const int m0 = (mb * MT + mt) * 16;
        const AT* Ap = A + (size_t)(m0 + lr) * K + quad * 8;
        floatx4 acc[NS];
#pragma unroll
        for (int s = 0; s < NS; s++) acc[s] = (floatx4){0.f, 0.f, 0.f, 0.f};
#pragma unroll
        for (int kc = 0; kc < KC; kc++) {
            short8 af = ld_frag(Ap + kc * 32);
#pragma unroll
            for (int s = 0; s < NS; s++)
                acc[s] = __builtin_amdgcn_mfma_f32_16x16x32_bf16(af, bf[s][kc], acc[s], 0, 0, 0);
        }
#pragma unroll
        for (int s = 0; s < NS; s++) {
            const int n = n0 + s * 16 + lr;
#pragma unroll
            for (int r = 0; r < 4; r++) {
                const int m = m0 + quad * 4 + r;
                const float val = acc[s][r] + biasv[s];
                if (OUTF32)
                    ((float*)Cv)[(size_t)m * N + n] = val;
                else
                    ((unsigned short*)Cv)[(size_t)m * N + n] = f2bf(val);
            }
        }
    }
}

// ---------------------------------------------------------------------------
// Pack rec_kernel fp32 [256][1024] -> f16 MFMA B-fragments, 64 strips
// (R7-verified).  Pm[(strip*8+kc)*64+lane].j =
//   f16( rec[kc*32+(lane>>4)*8+j][strip*16+(lane&15)] )
// ---------------------------------------------------------------------------
__global__ __launch_bounds__(256) void pack_rec_mfma(const float* __restrict__ rec,
                                                     uint4* __restrict__ Pm)
{
    const int idx = blockIdx.x * 256 + threadIdx.x;   // 0..32767
    const int lane = idx & 63;
    const int kc = (idx >> 6) & 7;
    const int strip = idx >> 9;
    const int q = lane >> 4, lr = lane & 15;
    const int col = strip * 16 + lr;
    const int k0 = kc * 32 + q * 8;
    union { unsigned short u[8]; uint4 v; } out;
#pragma unroll
    for (int j = 0; j < 8; j++) {
        const _Float16 h = (_Float16)rec[(size_t)(k0 + j) * FU + col];
        out.u[j] = __builtin_bit_cast(unsigned short, h);
    }
    Pm[idx] = out.v;
}

// ---------------------------------------------------------------------------
// Broadcast-A MFMA LSTM.  1 WG (512 thr / 8 waves, 2 waves/SIMD) per batch.
// Wave w strips: 2w,2w+1(i) 16+2w,17+2w(f) 32+2w,33+2w(g) resident
// (4 "+a" + 2 "+v"), 48+2w,49+2w(o) streamed from 128 KiB LDS.
// Per step/wave: 8 bcast A reads + 16 streamed-W reads + 64 MFMA (8 indep
// chains) + 32-lane gates.  ONE lgkm barrier/step (h parity dbuf).
// ---------------------------------------------------------------------------
template <typename XZT>
__global__ __launch_bounds__(512, 2)
void lstm_bcast(
    const XZT* __restrict__ xz,            // [B, T, 4U]
    const uint4* __restrict__ Pm,          // packed rec frags, 64 strips
    unsigned short* __restrict__ hs)       // [B, T, U] bf16 out
{
    const int b = blockIdx.x;
    const int tid = threadIdx.x;
    const int w = tid >> 6;                // wave 0..7
    const int lane = tid & 63;
    const int q = lane >> 4, lr = lane & 15;

    __shared__ uint4 Wl[16 * 8 * 64];                  // o-strips: 128 KiB
    __shared__ __align__(16) unsigned short h_pk[2][U];  // h f16 dbuf: 1 KiB

    // stage o-strips: slot sl (0..15) <- global strip 48 + 2*(sl>>1) + (sl&1)
    for (int i = tid; i < 16 * 8 * 64; i += 512) {
        const int sl = i >> 9;
        const int gs = 48 + 2 * (sl >> 1) + (sl & 1);
        Wl[i] = Pm[(size_t)gs * 512 + (i & 511)];
    }
    if (tid < 128) { ((unsigned int*)h_pk[0])[tid] = 0; }

    // resident strips: i-pair, f-pair, g-pair.
    uint4 Wa0[8], Wa1[8], Wa2[8], Wa3[8];   // -> AGPR (128)
    uint4 Wv0[8], Wv1[8];                   // -> arch VGPR (64)
#pragma unroll
    for (int kc = 0; kc < 8; kc++) {
        Wa0[kc] = Pm[((size_t)(2 * w + 0) * 8 + kc) * 64 + lane];       // i even
        Wa1[kc] = Pm[((size_t)(2 * w + 1) * 8 + kc) * 64 + lane];       // i odd
        Wa2[kc] = Pm[((size_t)(16 + 2 * w) * 8 + kc) * 64 + lane];      // f even
        Wa3[kc] = Pm[((size_t)(17 + 2 * w) * 8 + kc) * 64 + lane];      // f odd
        Wv0[kc] = Pm[((size_t)(32 + 2 * w) * 8 + kc) * 64 + lane];      // g even
        Wv1[kc] = Pm[((size_t)(33 + 2 * w) * 8 + kc) * 64 + lane];      // g odd
    }
    // Pin: 4 strips to AGPRs (MFMA reads B from AGPR natively on gfx950),
    // 2 strips to arch VGPRs.  128a + 64v W + acc/A/misc fits 256/wave.
#pragma unroll
    for (int kc = 0; kc < 8; kc++) {
        asm volatile("" : "+a"(Wa0[kc].x), "+a"(Wa0[kc].y), "+a"(Wa0[kc].z), "+a"(Wa0[kc].w));
        asm volatile("" : "+a"(Wa1[kc].x), "+a"(Wa1[kc].y), "+a"(Wa1[kc].z), "+a"(Wa1[kc].w));
        asm volatile("" : "+a"(Wa2[kc].x), "+a"(Wa2[kc].y), "+a"(Wa2[kc].z), "+a"(Wa2[kc].w));
        asm volatile("" : "+a"(Wa3[kc].x), "+a"(Wa3[kc].y), "+a"(Wa3[kc].z), "+a"(Wa3[kc].w));
        asm volatile("" : "+v"(Wv0[kc].x), "+v"(Wv0[kc].y), "+v"(Wv0[kc].z), "+v"(Wv0[kc].w));
        asm volatile("" : "+v"(Wv1[kc].x), "+v"(Wv1[kc].y), "+v"(Wv1[kc].z), "+v"(Wv1[kc].w));
    }
    __syncthreads();

    const XZT* xzb = xz + (size_t)b * T * FU;
    unsigned short* hsb = hs + (size_t)b * T * U;

    // gate-phase ownership: lanes q<2 own unit u = 32w + 16q + lr
    const int u = 32 * w + 16 * q + lr;
    const bool gact = (q < 2);

    float cst = 0.f;
    float xzi = 0.f, xzf = 0.f, xzg = 0.f, xzo = 0.f;
    if (gact) {
        xzi = ldxz1(xzb + u);        xzf = ldxz1(xzb + 256 + u);
        xzg = ldxz1(xzb + 512 + u);  xzo = ldxz1(xzb + 768 + u);
    }

    for (int t = 0; t < T; t++) {
        // prefetch next xz (vm stays in flight across the lgkm-only barrier)
        float xzi_n = 0.f, xzf_n = 0.f, xzg_n = 0.f, xzo_n = 0.f;
        if (gact && t + 1 < T) {
            const XZT* xt = xzb + (size_t)(t + 1) * FU;
            xzi_n = ldxz1(xt + u);       xzf_n = ldxz1(xt + 256 + u);
            xzg_n = ldxz1(xt + 512 + u); xzo_n = ldxz1(xt + 768 + u);
        }

        const char* hb = ((const char*)h_pk) + (t & 1) * 512;

        floatx4 a0 = {0.f,0.f,0.f,0.f}, a1 = {0.f,0.f,0.f,0.f};
        floatx4 a2 = {0.f,0.f,0.f,0.f}, a3 = {0.f,0.f,0.f,0.f};
        floatx4 a4 = {0.f,0.f,0.f,0.f}, a5 = {0.f,0.f,0.f,0.f};
        floatx4 a6 = {0.f,0.f,0.f,0.f}, a7 = {0.f,0.f,0.f,0.f};

        // A-frag (uniform per 16-lane group): h[kc*32 + q*8 .. +7] broadcast
        uint4 afc = *(const uint4*)(hb + q * 16), afn;
#pragma unroll
        for (int kc = 0; kc < 8; kc++) {
            if (kc < 7) afn = *(const uint4*)(hb + (kc + 1) * 64 + q * 16);
            const uint4 s6 = Wl[((w * 2 + 0) * 8 + kc) * 64 + lane];
            const uint4 s7 = Wl[((w * 2 + 1) * 8 + kc) * 64 + lane];
            const half8 av = h8c(afc);
            a0 = __builtin_amdgcn_mfma_f32_16x16x32_f16(av, h8c(Wa0[kc]), a0, 0, 0, 0);
            a1 = __builtin_amdgcn_mfma_f32_16x16x32_f16(av, h8c(Wa1[kc]), a1, 0, 0, 0);
            a2 = __builtin_amdgcn_mfma_f32_16x16x32_f16(av, h8c(Wa2[kc]), a2, 0, 0, 0);
            a3 = __builtin_amdgcn_mfma_f32_16x16x32_f16(av, h8c(Wa3[kc]), a3, 0, 0, 0);
            a4 = __builtin_amdgcn_mfma_f32_16x16x32_f16(av, h8c(Wv0[kc]), a4, 0, 0, 0);
            a5 = __builtin_amdgcn_mfma_f32_16x16x32_f16(av, h8c(Wv1[kc]), a5, 0, 0, 0);
            a6 = __builtin_amdgcn_mfma_f32_16x16x32_f16(av, h8c(s6), a6, 0, 0, 0);
            a7 = __builtin_amdgcn_mfma_f32_16x16x32_f16(av, h8c(s7), a7, 0, 0, 0);
            afc = afn;
        }

        // gates: every D row equals z, so acc*[0] is z for col lr of that
        // strip in EVERY lane.  q==0 -> even strips (units 32w+lr),
        // q==1 -> odd strips (units 32w+16+lr).
        if (gact) {
            float zi_, zf_, zg_, zo_;
            if (q == 0) { zi_ = a0[0]; zf_ = a2[0]; zg_ = a4[0]; zo_ = a6[0]; }
            else        { zi_ = a1[0]; zf_ = a3[0]; zg_ = a5[0]; zo_ = a7[0]; }
            const float iv = sigmf(zi_ + xzi);
            const float fv = sigmf(zf_ + xzf);
            const float gv = tanhfast(zg_ + xzg);
            const float ov = sigmf(zo_ + xzo);
            cst = fv * cst + iv * gv;
            const float hv = ov * tanhfast(cst);
            h_pk[(t + 1) & 1][u] = __builtin_bit_cast(unsigned short, (_Float16)hv);
            hsb[(size_t)t * U + u] = f2bf(hv);
        }
        BAR();   // h_{t+1} visible; reads of h_t complete (anti-dep safe)

        xzi = xzi_n; xzf = xzf_n; xzg = xzg_n; xzo = xzo_n;
    }
}

// ---------------------------------------------------------------------------
extern "C" void kernel_launch(void* const* d_in, const int* in_sizes, int n_in,
                              void* d_out, int out_size, void* d_ws, size_t ws_size,
                              hipStream_t stream)
{
    const float* x    = (const float*)d_in[0];
    const float* w_in = (const float*)d_in[1];
    const float* b_in = (const float*)d_in[2];
    const float* kern = (const float*)d_in[3];
    const float* rec  = (const float*)d_in[4];
    const float* bias = (const float*)d_in[5];
    const float* wout = (const float*)d_in[6];
    const float* bout = (const float*)d_in[7];

    char* ws = (char*)d_ws;
    const size_t rec_bytes = (size_t)64 * 8 * 64 * 16;    // 512 KiB packed W frags
    const size_t xin_bytes = (size_t)M * D * 2;           // 16 MiB
    const size_t hs_bytes  = (size_t)M * U * 2;           // 16 MiB
    const size_t xz32_bytes = (size_t)M * FU * 4;         // 128 MiB
    const size_t base = rec_bytes + xin_bytes + hs_bytes;

    uint4* Pm = (uint4*)ws;
    unsigned short* xin_bf = (unsigned short*)(ws + rec_bytes);
    unsigned short* hs_bf  = (unsigned short*)(ws + rec_bytes + xin_bytes);
    char* xz_raw = ws + base;

    const bool use_f32 = ws_size >= base + xz32_bytes;

    // pack rec_kernel -> f16 MFMA fragment layout (every launch; ws re-poisoned)
    pack_rec_mfma<<<128, 256, 0, stream>>>(rec, Pm);

    // GEMM1: xin = bf16(x @ w_in + b_in)   [M,512]x[512,256]
    gemm_mfma<512, 256, 16, 2, false><<<(256 / 32) * (M / 256), 64, 0, stream>>>(
        x, w_in, b_in, (void*)xin_bf);

    if (use_f32) {
        float* xzp = (float*)xz_raw;
        // GEMM2: xz = fp32(xin @ kernel + bias)  [M,256]x[256,1024]
        gemm_mfma<256, 1024, 16, 2, true><<<(1024 / 32) * (M / 256), 64, 0, stream>>>(
            xin_bf, kern, bias, (void*)xzp);
        lstm_bcast<float><<<Bsz, 512, 0, stream>>>(xzp, Pm, hs_bf);
    } else {
        unsigned short* xzp = (unsigned short*)xz_raw;
        gemm_mfma<256, 1024, 16, 2, false><<<(1024 / 32) * (M / 256), 64, 0, stream>>>(
            xin_bf, kern, bias, (void*)xzp);
        lstm_bcast<unsigned short><<<Bsz, 512, 0, stream>>>(xzp, Pm, hs_bf);
    }

    // GEMM3: out = fp32(hs @ w_out + b_out)  [M,256]x[256,256]
    gemm_mfma<256, 256, 16, 2, true><<<(256 / 32) * (M / 256), 64, 0, stream>>>(
        hs_bf, wout, bout, d_out);
}